// Round 12
// baseline (278.967 us; speedup 1.0000x reference)
//
#include <hip/hip_runtime.h>

#define NEG_SLOPE 0.04f
#define MASK_VAL  -9.0e15f

#define FMA4(acc, s, w4) \
  acc.x = fmaf(s, w4.x, acc.x); acc.y = fmaf(s, w4.y, acc.y); \
  acc.z = fmaf(s, w4.z, acc.z); acc.w = fmaf(s, w4.w, acc.w)

namespace {
constexpr int Bz = 128;   // batch
constexpr int NN = 64;    // nodes (1 robot + 63 humans)
constexpr int XD = 128;   // embedding dim
constexpr int HID = 64;   // embed hidden width
}

// ---------------------------------------------------------------------------
// GAT layer body, c-blocked. Block = (batch b, row-half h). 512 threads.
// LDS (56 KB total -> 2 blocks/CU):
//   Ns  [64][128]  node features                      8192 floats
//   VU  [64][64]   V col-block, float4-chunk swizzle  4096 floats (alias: hs)
//   UsAs[32][64]   U' col-block; later attn weights   2048 floats
// Loop cb=0..3 over 64-col blocks: {T-V + T-U -> barrier -> S partial ->
// barrier}; then softmax (register), As write, barrier, PV.
// T-V: thread (cq=t&15, g=t>>4) -> nodes 2g,2g+1, col quad cb*64+4cq.
// T-U: same thread -> local row g, same quad.
// S:   lane l = target j; wave w -> rows 4w..4w+3; swizzled VU read hits
//      the ds_b128 8-phase floor (chunk c stored at c ^ (row&15)).
// PV:  thread (grp=t>>5, l32) -> rows grp,grp+16, dims 4*l32..+3.
// ---------------------------------------------------------------------------
__device__ __forceinline__ void gat_layer(
    const float* __restrict__ Ns, float* __restrict__ VU, float* __restrict__ UsAs,
    const float* __restrict__ W1, const float* __restrict__ b1,
    const float* __restrict__ W2, const float* __restrict__ b2,
    int h, int t, float4& o0, float4& o1)
{
  const int w  = t >> 6, l = t & 63;
  const int cq = t & 15;          // col quad within the 64-col block
  const int g  = t >> 4;          // 0..31
  const int n0 = 2 * g;           // T-V nodes n0, n0+1
  const int jx = l & 15;

  float e[4] = {0.f, 0.f, 0.f, 0.f};

  for (int cb = 0; cb < 4; ++cb) {
    const int c0 = cb * 64 + 4 * cq;
    // ---- T-V (nodes n0, n0+1) + T-U (row g), cols c0..c0+3 ----
    float4 v0a = {0.f,0.f,0.f,0.f}, v1a = {0.f,0.f,0.f,0.f};
    float4 ua  = *reinterpret_cast<const float4*>(&b1[c0]);
    const float* x0p = &Ns[n0 * XD];
    const float* x1p = &Ns[(n0 + 1) * XD];
    const float* xrp = &Ns[(32 * h + g) * XD];
#pragma unroll 2
    for (int ks = 0; ks < XD; ks += 4) {
      float4 wv0 = *reinterpret_cast<const float4*>(&W1[(XD + ks    ) * 256 + c0]);
      float4 wv1 = *reinterpret_cast<const float4*>(&W1[(XD + ks + 1) * 256 + c0]);
      float4 wv2 = *reinterpret_cast<const float4*>(&W1[(XD + ks + 2) * 256 + c0]);
      float4 wv3 = *reinterpret_cast<const float4*>(&W1[(XD + ks + 3) * 256 + c0]);
      float4 wu0 = *reinterpret_cast<const float4*>(&W1[(ks    ) * 256 + c0]);
      float4 wu1 = *reinterpret_cast<const float4*>(&W1[(ks + 1) * 256 + c0]);
      float4 wu2 = *reinterpret_cast<const float4*>(&W1[(ks + 2) * 256 + c0]);
      float4 wu3 = *reinterpret_cast<const float4*>(&W1[(ks + 3) * 256 + c0]);
      const float4 xa = *reinterpret_cast<const float4*>(&x0p[ks]);   // broadcast
      const float4 xb = *reinterpret_cast<const float4*>(&x1p[ks]);
      const float4 xc = *reinterpret_cast<const float4*>(&xrp[ks]);
      FMA4(v0a, xa.x, wv0); FMA4(v0a, xa.y, wv1); FMA4(v0a, xa.z, wv2); FMA4(v0a, xa.w, wv3);
      FMA4(v1a, xb.x, wv0); FMA4(v1a, xb.y, wv1); FMA4(v1a, xb.z, wv2); FMA4(v1a, xb.w, wv3);
      FMA4(ua,  xc.x, wu0); FMA4(ua,  xc.y, wu1); FMA4(ua,  xc.z, wu2); FMA4(ua,  xc.w, wu3);
    }
    *reinterpret_cast<float4*>(&VU[n0 * 64 + ((cq ^ (n0 & 15)) << 2)])       = v0a;
    *reinterpret_cast<float4*>(&VU[(n0+1) * 64 + ((cq ^ ((n0+1) & 15)) << 2)]) = v1a;
    *reinterpret_cast<float4*>(&UsAs[g * 64 + 4 * cq]) = ua;
    __syncthreads();

    // ---- S partial: e[q] += sum over this col-block ----
    for (int q4 = 0; q4 < 16; ++q4) {
      const float4 v4 = *reinterpret_cast<const float4*>(&VU[l * 64 + ((q4 ^ jx) << 2)]);
      const float4 w4 = *reinterpret_cast<const float4*>(&W2[cb * 64 + 4 * q4]);  // uniform
#pragma unroll
      for (int q = 0; q < 4; ++q) {
        const float4 u4 = *reinterpret_cast<const float4*>(&UsAs[(4*w + q) * 64 + 4 * q4]); // broadcast
        e[q] = fmaf(fmaxf(u4.x + v4.x, 0.f), w4.x, e[q]);
        e[q] = fmaf(fmaxf(u4.y + v4.y, 0.f), w4.y, e[q]);
        e[q] = fmaf(fmaxf(u4.z + v4.z, 0.f), w4.z, e[q]);
        e[q] = fmaf(fmaxf(u4.w + v4.w, 0.f), w4.w, e[q]);
      }
    }
    __syncthreads();   // before next cb overwrites VU / UsAs
  }

  // ---- softmax over j (lane = j) ----
  float att[4];
  const float bias2 = b2[0];
#pragma unroll
  for (int q = 0; q < 4; ++q) {
    float s = e[q] + bias2;
    s = s > 0.f ? s : NEG_SLOPE * s;                 // LeakyReLU(0.04)
    const int gi = 32 * h + 4 * w + q;
    if (gi > 0 && l == 0) s = MASK_VAL;              // humans can't attend robot
    float m = s;
#pragma unroll
    for (int off = 32; off > 0; off >>= 1) m = fmaxf(m, __shfl_xor(m, off));
    const float p = __expf(s - m);
    float sum = p;
#pragma unroll
    for (int off = 32; off > 0; off >>= 1) sum += __shfl_xor(sum, off);
    att[q] = p / sum;
  }
  // As overwrites UsAs (all S reads completed at loop-end barrier)
#pragma unroll
  for (int q = 0; q < 4; ++q) UsAs[(4*w + q) * 64 + l] = att[q];
  __syncthreads();

  // ---- PV: H[r] = att[r] @ Ns ----
  {
    const int grp = t >> 5, d4 = (t & 31) << 2;
    float4 a0 = {0.f,0.f,0.f,0.f}, a1 = {0.f,0.f,0.f,0.f};
    for (int j = 0; j < NN; ++j) {
      const float4 x4 = *reinterpret_cast<const float4*>(&Ns[j * XD + d4]);
      const float wA = UsAs[grp * 64 + j];
      const float wB = UsAs[(grp + 16) * 64 + j];
      FMA4(a0, wA, x4);
      FMA4(a1, wB, x4);
    }
    o0 = a0; o1 = a1;
  }
}

// ---------------------------------------------------------------------------
// Kernel 1: embed (hs aliased into VU region) + GAT layer 1 -> H1g, Xg.
// ---------------------------------------------------------------------------
__global__ __launch_bounds__(512, 4) void layer1_kernel(
    const float* __restrict__ robot, const float* __restrict__ human,
    const float* __restrict__ wrW1, const float* __restrict__ wrb1,
    const float* __restrict__ wrW2, const float* __restrict__ wrb2,
    const float* __restrict__ whW1, const float* __restrict__ whb1,
    const float* __restrict__ whW2, const float* __restrict__ whb2,
    const float* __restrict__ W1, const float* __restrict__ b1,
    const float* __restrict__ W2, const float* __restrict__ b2,
    float* __restrict__ Xg, float* __restrict__ H1g)
{
  __shared__ float smem[14336];        // 56 KB -> 2 blocks/CU
  float* Xs   = smem;                  // [64][128]
  float* VU   = smem + 8192;           // [64][64] swizzled; embed alias hs[64][64]
  float* UsAs = smem + 12288;          // [32][64]
  float* hs   = VU;

  const int b = blockIdx.x >> 1, h = blockIdx.x & 1;
  const int t = threadIdx.x;

  // ---- E1: hidden layer, 64 nodes x 64 ----
  for (int v = t; v < NN * HID; v += 512) {
    const int n = v >> 6, k = v & 63;
    float acc;
    if (n == 0) {
      acc = wrb1[k];
      for (int j = 0; j < 9; ++j) acc = fmaf(robot[b * 9 + j], wrW1[j * HID + k], acc);
    } else {
      const float* in = human + (b * 63 + n - 1) * 5;
      acc = whb1[k];
      for (int j = 0; j < 5; ++j) acc = fmaf(in[j], whW1[j * HID + k], acc);
    }
    hs[v] = fmaxf(acc, 0.f);
  }
  __syncthreads();

  // ---- E2: output layer; thread (d=t&127, which=t>>7), nodes 4c+which ----
  {
    const int d = t & 127, which = t >> 7;
    float xacc[16];
#pragma unroll
    for (int c = 0; c < 16; ++c) xacc[c] = whb2[d];

    for (int k4 = 0; k4 < 16; ++k4) {
      float w4[4];
#pragma unroll
      for (int kk = 0; kk < 4; ++kk) w4[kk] = whW2[(4 * k4 + kk) * XD + d];
#pragma unroll
      for (int c = 0; c < 16; ++c) {
        const float4 h4 = *reinterpret_cast<const float4*>(&hs[(4 * c + which) * HID + 4 * k4]);
        xacc[c] = fmaf(h4.x, w4[0], xacc[c]);
        xacc[c] = fmaf(h4.y, w4[1], xacc[c]);
        xacc[c] = fmaf(h4.z, w4[2], xacc[c]);
        xacc[c] = fmaf(h4.w, w4[3], xacc[c]);
      }
    }
    if (which == 0) {                  // redo global node 0 with robot weights
      float a = wrb2[d];
#pragma unroll 8
      for (int k = 0; k < HID; ++k) a = fmaf(hs[k], wrW2[k * XD + d], a);
      xacc[0] = a;
    }
#pragma unroll
    for (int c = 0; c < 16; ++c) {
      const int n = 4 * c + which;
      const float val = fmaxf(xacc[c], 0.f);
      Xs[n * XD + d] = val;
      if ((n >> 5) == h) Xg[((size_t)(b * NN + n)) * XD + d] = val;
    }
  }
  __syncthreads();   // Xs ready; hs (VU region) dead

  float4 a0, a1;
  gat_layer(Xs, VU, UsAs, W1, b1, W2, b2, h, t, a0, a1);

  const int grp = t >> 5, d4 = (t & 31) << 2;
  const int nA = 32 * h + grp, nB = nA + 16;
  *reinterpret_cast<float4*>(&H1g[((size_t)(b * NN + nA)) * XD + d4]) = a0;
  *reinterpret_cast<float4*>(&H1g[((size_t)(b * NN + nB)) * XD + d4]) = a1;
}

// ---------------------------------------------------------------------------
// Kernel 2: stage H1 -> GAT layer 2 -> out = H2 + H1 + X (skip fused).
// ---------------------------------------------------------------------------
__global__ __launch_bounds__(512, 4) void layer2_kernel(
    const float* __restrict__ H1g, const float* __restrict__ Xg,
    const float* __restrict__ W1, const float* __restrict__ b1,
    const float* __restrict__ W2, const float* __restrict__ b2,
    float* __restrict__ out)
{
  __shared__ float smem[14336];        // 56 KB
  float* Ys   = smem;                  // [64][128] = staged H1
  float* VU   = smem + 8192;
  float* UsAs = smem + 12288;

  const int b = blockIdx.x >> 1, h = blockIdx.x & 1;
  const int t = threadIdx.x;

  const float* Hb = H1g + (size_t)b * NN * XD;
  for (int idx = t; idx < NN * XD / 4; idx += 512)
    *reinterpret_cast<float4*>(Ys + idx * 4) =
        *reinterpret_cast<const float4*>(Hb + idx * 4);
  __syncthreads();

  float4 a0, a1;
  gat_layer(Ys, VU, UsAs, W1, b1, W2, b2, h, t, a0, a1);

  const int grp = t >> 5, d4 = (t & 31) << 2;
  const int nA = 32 * h + grp, nB = nA + 16;
  const float4 y0 = *reinterpret_cast<const float4*>(&Ys[nA * XD + d4]);
  const float4 y1 = *reinterpret_cast<const float4*>(&Ys[nB * XD + d4]);
  const float4 x0 = *reinterpret_cast<const float4*>(&Xg[((size_t)(b * NN + nA)) * XD + d4]);
  const float4 x1 = *reinterpret_cast<const float4*>(&Xg[((size_t)(b * NN + nB)) * XD + d4]);
  a0.x += y0.x + x0.x; a0.y += y0.y + x0.y; a0.z += y0.z + x0.z; a0.w += y0.w + x0.w;
  a1.x += y1.x + x1.x; a1.y += y1.y + x1.y; a1.z += y1.z + x1.z; a1.w += y1.w + x1.w;
  *reinterpret_cast<float4*>(&out[((size_t)(b * NN + nA)) * XD + d4]) = a0;
  *reinterpret_cast<float4*>(&out[((size_t)(b * NN + nB)) * XD + d4]) = a1;
}

// ---------------------------------------------------------------------------
extern "C" void kernel_launch(void* const* d_in, const int* in_sizes, int n_in,
                              void* d_out, int out_size, void* d_ws, size_t ws_size,
                              hipStream_t stream) {
  const float* robot = (const float*)d_in[0];
  const float* human = (const float*)d_in[1];
  const float* wrW1  = (const float*)d_in[2];
  const float* wrb1  = (const float*)d_in[3];
  const float* wrW2  = (const float*)d_in[4];
  const float* wrb2  = (const float*)d_in[5];
  const float* whW1  = (const float*)d_in[6];
  const float* whb1  = (const float*)d_in[7];
  const float* whW2  = (const float*)d_in[8];
  const float* whb2  = (const float*)d_in[9];
  const float* g0W1  = (const float*)d_in[10];
  const float* g0b1  = (const float*)d_in[11];
  const float* g0W2  = (const float*)d_in[12];
  const float* g0b2  = (const float*)d_in[13];
  const float* g1W1  = (const float*)d_in[14];
  const float* g1b1  = (const float*)d_in[15];
  const float* g1W2  = (const float*)d_in[16];
  const float* g1b2  = (const float*)d_in[17];
  float* out = (float*)d_out;

  float* Xg  = (float*)d_ws;                       // 4 MB [B,64,128]
  float* H1g = Xg + (size_t)Bz * NN * XD;          // 4 MB [B,64,128]

  layer1_kernel<<<Bz * 2, 512, 0, stream>>>(robot, human, wrW1, wrb1, wrW2, wrb2,
                                            whW1, whb1, whW2, whb2,
                                            g0W1, g0b1, g0W2, g0b2, Xg, H1g);
  layer2_kernel<<<Bz * 2, 512, 0, stream>>>(H1g, Xg, g1W1, g1b1, g1W2, g1b2, out);
}

// Round 13
// 229.149 us; speedup vs baseline: 1.2174x; 1.2174x over previous
//
#include <hip/hip_runtime.h>

#define NEG_SLOPE 0.04f
#define MASK_VAL  -9.0e15f

#define FMA4(acc, s, w4) \
  acc.x = fmaf(s, w4.x, acc.x); acc.y = fmaf(s, w4.y, acc.y); \
  acc.z = fmaf(s, w4.z, acc.z); acc.w = fmaf(s, w4.w, acc.w)

namespace {
constexpr int Bz = 128;   // batch
constexpr int NN = 64;    // nodes (1 robot + 63 humans)
constexpr int XD = 128;   // embedding dim
constexpr int HID = 64;   // embed hidden width
}

__device__ __forceinline__ float rl_f(float v, int lane) {
  return __int_as_float(__builtin_amdgcn_readlane(__float_as_int(v), lane));
}

// ---------------------------------------------------------------------------
// Kernel 1: node embeddings (validated in R5 run). 4 blocks/batch, 16 nodes.
// ---------------------------------------------------------------------------
__global__ __launch_bounds__(256) void embed_kernel(
    const float* __restrict__ robot, const float* __restrict__ human,
    const float* __restrict__ wrW1, const float* __restrict__ wrb1,
    const float* __restrict__ wrW2, const float* __restrict__ wrb2,
    const float* __restrict__ whW1, const float* __restrict__ whb1,
    const float* __restrict__ whW2, const float* __restrict__ whb2,
    float* __restrict__ X)
{
  __shared__ float hs[16 * HID];   // 4 KB
  const int b  = blockIdx.x >> 2;
  const int rg = blockIdx.x & 3;   // nodes rg*16 .. rg*16+15
  const int t  = threadIdx.x;

  for (int v = t; v < 16 * HID; v += 256) {
    const int nl = v >> 6, k = v & 63;
    const int n  = rg * 16 + nl;
    float acc;
    if (n == 0) {
      acc = wrb1[k];
      for (int j = 0; j < 9; ++j) acc = fmaf(robot[b * 9 + j], wrW1[j * HID + k], acc);
    } else {
      const float* in = human + (b * 63 + n - 1) * 5;
      acc = whb1[k];
      for (int j = 0; j < 5; ++j) acc = fmaf(in[j], whW1[j * HID + k], acc);
    }
    hs[v] = fmaxf(acc, 0.f);
  }
  __syncthreads();

  const int d = t & 127, which = t >> 7;
  float acc[8];
#pragma unroll
  for (int c = 0; c < 8; ++c) acc[c] = whb2[d];

  for (int k4 = 0; k4 < 16; ++k4) {
    float w4[4];
#pragma unroll
    for (int kk = 0; kk < 4; ++kk) w4[kk] = whW2[(4 * k4 + kk) * XD + d];
#pragma unroll
    for (int c = 0; c < 8; ++c) {
      const float4 h4 = *reinterpret_cast<const float4*>(&hs[(2 * c + which) * HID + 4 * k4]);
      acc[c] = fmaf(h4.x, w4[0], acc[c]);
      acc[c] = fmaf(h4.y, w4[1], acc[c]);
      acc[c] = fmaf(h4.z, w4[2], acc[c]);
      acc[c] = fmaf(h4.w, w4[3], acc[c]);
    }
  }
  if (rg == 0 && which == 0) {        // redo node 0 with robot weights
    float a = wrb2[d];
#pragma unroll 8
    for (int k = 0; k < HID; ++k) a = fmaf(hs[k], wrW2[k * XD + d], a);
    acc[0] = a;
  }
#pragma unroll
  for (int c = 0; c < 8; ++c) {
    const int n = rg * 16 + 2 * c + which;
    X[(size_t)(b * NN + n) * XD + d] = fmaxf(acc[c], 0.f);
  }
}

// ---------------------------------------------------------------------------
// Kernel 2/4: V-transform, non-redundant: Vg = Xin @ W1[128:256,:].
// 1024 blocks (8 rows each), 256 thr, 4 KB LDS -> 4 blocks/CU.
// ---------------------------------------------------------------------------
__global__ __launch_bounds__(256) void vtrans_kernel(
    const float* __restrict__ Xin, const float* __restrict__ W1,
    float* __restrict__ Vg)
{
  __shared__ float Xs[8 * XD];   // 4 KB
  const int t = threadIdx.x;
  const int base = blockIdx.x * 8;
  reinterpret_cast<float4*>(Xs)[t] =
      reinterpret_cast<const float4*>(Xin + (size_t)base * XD)[t];  // 256 f4 = 8 rows
  __syncthreads();

  float acc[8];
#pragma unroll
  for (int n = 0; n < 8; ++n) acc[n] = 0.f;
  for (int k = 0; k < XD; k += 4) {
    const float w0 = W1[(XD + k    ) * 256 + t];
    const float w1 = W1[(XD + k + 1) * 256 + t];
    const float w2 = W1[(XD + k + 2) * 256 + t];
    const float w3 = W1[(XD + k + 3) * 256 + t];
#pragma unroll
    for (int n = 0; n < 8; ++n) {
      const float4 x4 = *reinterpret_cast<const float4*>(&Xs[n * XD + k]);
      acc[n] = fmaf(x4.x, w0, acc[n]);
      acc[n] = fmaf(x4.y, w1, acc[n]);
      acc[n] = fmaf(x4.z, w2, acc[n]);
      acc[n] = fmaf(x4.w, w3, acc[n]);
    }
  }
#pragma unroll
  for (int n = 0; n < 8; ++n)
    Vg[(size_t)(base + n) * 256 + t] = acc[n];
}

// ---------------------------------------------------------------------------
// Kernel 3/5: attention. Block = (b, rg): 16 rows. 512 thr = 8 waves.
// LDS 70656 B -> 2 blocks/CU; grid 512 -> 16 waves/CU (4/SIMD).
//   Vs [64][256] swizzled (chunk c -> c^(j&7): 8 broadcast groups x 8 chunks
//       = 32 banks, conflict-free b128 reads)     65536 B
//   As [16][64]  attn weights                      4096 B
//   W2s[256]                                       1024 B
// T-U: wave w owns local rows 2w,2w+1; lane l owns cols 4l..4l+3 (registers,
//      W1 reads fully coalesced 1KB/wave). No Us LDS.
// S:   lane = j; U broadcast via v_readlane from lane c4 (uniform SGPR).
// PV:  thread (grp=t>>5 -> local row, l32 -> dims); Xpv from global (L1 bcast).
// Barriers: 2 (stage->S, As->PV).
// ---------------------------------------------------------------------------
__global__ __launch_bounds__(512, 4) void attn_kernel(
    const float* __restrict__ Vg, const float* __restrict__ Xu,
    const float* __restrict__ Xskip,
    const float* __restrict__ W1, const float* __restrict__ b1,
    const float* __restrict__ W2g, const float* __restrict__ b2g,
    float* __restrict__ out, int add_skip)
{
  __shared__ float smem[17664];        // 70656 B
  float* Vs  = smem;                   // [64][256] swizzled
  float* As  = smem + 16384;           // [16][64]
  float* W2s = smem + 17408;           // [256]

  const int b  = blockIdx.x >> 2;
  const int rg = blockIdx.x & 3;       // local rows rg*16 .. rg*16+15
  const int t  = threadIdx.x;
  const int w  = t >> 6, l = t & 63;

  // ---- stage V (swizzled) + W2 ----
  const float* Vb = Vg + (size_t)b * NN * 256;
  for (int cc = t; cc < NN * 64; cc += 512) {
    const int j = cc >> 6, c = cc & 63;
    const float4 v = *reinterpret_cast<const float4*>(Vb + j * 256 + (c << 2));
    *reinterpret_cast<float4*>(Vs + j * 256 + ((c ^ (j & 7)) << 2)) = v;
  }
  if (t < 64)
    reinterpret_cast<float4*>(W2s)[t] = reinterpret_cast<const float4*>(W2g)[t];

  // ---- T-U (registers; overlaps the staging loads, no LDS use) ----
  float4 ua0, ua1;
  {
    const float4 bi = *reinterpret_cast<const float4*>(&b1[l << 2]);
    ua0 = bi; ua1 = bi;
    const float* x0 = Xu + (size_t)(b * NN + rg * 16 + 2 * w) * XD;
    const float* x1 = x0 + XD;
#pragma unroll 2
    for (int ks = 0; ks < XD; ks += 4) {
      const float4 wu0 = *reinterpret_cast<const float4*>(&W1[(ks    ) * 256 + (l << 2)]);
      const float4 wu1 = *reinterpret_cast<const float4*>(&W1[(ks + 1) * 256 + (l << 2)]);
      const float4 wu2 = *reinterpret_cast<const float4*>(&W1[(ks + 2) * 256 + (l << 2)]);
      const float4 wu3 = *reinterpret_cast<const float4*>(&W1[(ks + 3) * 256 + (l << 2)]);
      const float4 xa = *reinterpret_cast<const float4*>(&x0[ks]);   // uniform
      const float4 xb = *reinterpret_cast<const float4*>(&x1[ks]);   // uniform
      FMA4(ua0, xa.x, wu0); FMA4(ua0, xa.y, wu1); FMA4(ua0, xa.z, wu2); FMA4(ua0, xa.w, wu3);
      FMA4(ua1, xb.x, wu0); FMA4(ua1, xb.y, wu1); FMA4(ua1, xb.z, wu2); FMA4(ua1, xb.w, wu3);
    }
  }
  __syncthreads();   // Vs + W2s visible

  // ---- S: e[q][j], lane = j; u broadcast via readlane ----
  float att0, att1;
  {
    const int jx = l & 7;
    float e0 = 0.f, e1 = 0.f;
    for (int c4 = 0; c4 < 64; ++c4) {
      const float4 v4 = *reinterpret_cast<const float4*>(&Vs[l * 256 + ((c4 ^ jx) << 2)]);
      const float4 w4 = *reinterpret_cast<const float4*>(&W2s[c4 << 2]);   // broadcast
      const float4 u0 = make_float4(rl_f(ua0.x, c4), rl_f(ua0.y, c4),
                                    rl_f(ua0.z, c4), rl_f(ua0.w, c4));
      const float4 u1 = make_float4(rl_f(ua1.x, c4), rl_f(ua1.y, c4),
                                    rl_f(ua1.z, c4), rl_f(ua1.w, c4));
      e0 = fmaf(fmaxf(u0.x + v4.x, 0.f), w4.x, e0);
      e0 = fmaf(fmaxf(u0.y + v4.y, 0.f), w4.y, e0);
      e0 = fmaf(fmaxf(u0.z + v4.z, 0.f), w4.z, e0);
      e0 = fmaf(fmaxf(u0.w + v4.w, 0.f), w4.w, e0);
      e1 = fmaf(fmaxf(u1.x + v4.x, 0.f), w4.x, e1);
      e1 = fmaf(fmaxf(u1.y + v4.y, 0.f), w4.y, e1);
      e1 = fmaf(fmaxf(u1.z + v4.z, 0.f), w4.z, e1);
      e1 = fmaf(fmaxf(u1.w + v4.w, 0.f), w4.w, e1);
    }
    const float bias2 = b2g[0];
    const int gi0 = rg * 16 + 2 * w;
    // q = 0
    {
      float s = e0 + bias2;
      s = s > 0.f ? s : NEG_SLOPE * s;
      if (gi0 > 0 && l == 0) s = MASK_VAL;
      float m = s;
#pragma unroll
      for (int off = 32; off > 0; off >>= 1) m = fmaxf(m, __shfl_xor(m, off));
      const float p = __expf(s - m);
      float sum = p;
#pragma unroll
      for (int off = 32; off > 0; off >>= 1) sum += __shfl_xor(sum, off);
      att0 = p / sum;
    }
    // q = 1
    {
      float s = e1 + bias2;
      s = s > 0.f ? s : NEG_SLOPE * s;
      if (l == 0) s = MASK_VAL;                   // gi0+1 >= 1 always
      float m = s;
#pragma unroll
      for (int off = 32; off > 0; off >>= 1) m = fmaxf(m, __shfl_xor(m, off));
      const float p = __expf(s - m);
      float sum = p;
#pragma unroll
      for (int off = 32; off > 0; off >>= 1) sum += __shfl_xor(sum, off);
      att1 = p / sum;
    }
  }
  As[(2 * w) * 64 + l]     = att0;
  As[(2 * w + 1) * 64 + l] = att1;
  __syncthreads();

  // ---- PV: H[row] = att[row] @ Xu ----
  const int grp = t >> 5, d4 = (t & 31) << 2;
  const int row = rg * 16 + grp;
  float4 a = {0.f, 0.f, 0.f, 0.f};
  const float* Xb = Xu + (size_t)b * NN * XD;
#pragma unroll 4
  for (int j = 0; j < NN; ++j) {
    const float4 x4 = *reinterpret_cast<const float4*>(&Xb[j * XD + d4]);
    const float wA = As[grp * 64 + j];
    FMA4(a, wA, x4);
  }
  if (add_skip) {   // out = H2 + H1 + X ; Xu IS H1 here
    const float4 h1 = *reinterpret_cast<const float4*>(&Xb[row * XD + d4]);
    const float4 x0 = *reinterpret_cast<const float4*>(&Xskip[((size_t)(b * NN + row)) * XD + d4]);
    a.x += h1.x + x0.x; a.y += h1.y + x0.y; a.z += h1.z + x0.z; a.w += h1.w + x0.w;
  }
  *reinterpret_cast<float4*>(&out[((size_t)(b * NN + row)) * XD + d4]) = a;
}

// ---------------------------------------------------------------------------
extern "C" void kernel_launch(void* const* d_in, const int* in_sizes, int n_in,
                              void* d_out, int out_size, void* d_ws, size_t ws_size,
                              hipStream_t stream) {
  const float* robot = (const float*)d_in[0];
  const float* human = (const float*)d_in[1];
  const float* wrW1  = (const float*)d_in[2];
  const float* wrb1  = (const float*)d_in[3];
  const float* wrW2  = (const float*)d_in[4];
  const float* wrb2  = (const float*)d_in[5];
  const float* whW1  = (const float*)d_in[6];
  const float* whb1  = (const float*)d_in[7];
  const float* whW2  = (const float*)d_in[8];
  const float* whb2  = (const float*)d_in[9];
  const float* g0W1  = (const float*)d_in[10];
  const float* g0b1  = (const float*)d_in[11];
  const float* g0W2  = (const float*)d_in[12];
  const float* g0b2  = (const float*)d_in[13];
  const float* g1W1  = (const float*)d_in[14];
  const float* g1b1  = (const float*)d_in[15];
  const float* g1W2  = (const float*)d_in[16];
  const float* g1b2  = (const float*)d_in[17];
  float* out = (float*)d_out;

  float* Xg  = (float*)d_ws;                       // 4 MB [B,64,128]
  float* H1g = Xg  + (size_t)Bz * NN * XD;         // 4 MB [B,64,128]
  float* Vg  = H1g + (size_t)Bz * NN * XD;         // 8 MB [B*64,256]

  embed_kernel<<<Bz * 4, 256, 0, stream>>>(robot, human, wrW1, wrb1, wrW2, wrb2,
                                           whW1, whb1, whW2, whb2, Xg);
  vtrans_kernel<<<Bz * NN / 8, 256, 0, stream>>>(Xg, g0W1, Vg);
  attn_kernel<<<Bz * 4, 512, 0, stream>>>(Vg, Xg, nullptr,
                                          g0W1, g0b1, g0W2, g0b2, H1g, 0);
  vtrans_kernel<<<Bz * NN / 8, 256, 0, stream>>>(H1g, g1W1, Vg);
  attn_kernel<<<Bz * 4, 512, 0, stream>>>(Vg, H1g, Xg,
                                          g1W1, g1b1, g1W2, g1b2, out, 1);
}

// Round 14
// 213.306 us; speedup vs baseline: 1.3078x; 1.0743x over previous
//
#include <hip/hip_runtime.h>

#define NEG_SLOPE 0.04f
#define MASK_VAL  -9.0e15f

#define FMA4(acc, s, w4) \
  acc.x = fmaf(s, w4.x, acc.x); acc.y = fmaf(s, w4.y, acc.y); \
  acc.z = fmaf(s, w4.z, acc.z); acc.w = fmaf(s, w4.w, acc.w)

namespace {
constexpr int Bz = 128;   // batch
constexpr int NN = 64;    // nodes (1 robot + 63 humans)
constexpr int XD = 128;   // embedding dim
constexpr int HID = 64;   // embed hidden width
}

__device__ __forceinline__ float rl_f(float v, int lane) {
  return __int_as_float(__builtin_amdgcn_readlane(__float_as_int(v), lane));
}

// XCD-aware swizzle for grid=512 (= Bz*4). HW assigns XCD ~ blockIdx%8.
// Batch b -> XCD b/16, so producer (uvtrans) and all 4 consumer blocks of a
// batch share one XCD's L2 (per-XCD working set ~2.5MB < 4MB).
__device__ __forceinline__ void swz512(int h, int& b, int& q) {
  const int xcd = h & 7, slot = h >> 3;   // slot 0..63
  b = xcd * 16 + (slot >> 2);             // batch 0..127
  q = slot & 3;                           // quarter 0..3
}

// ---------------------------------------------------------------------------
// Kernel 1: node embeddings (validated R5/R13). 4 blocks/batch, 16 nodes.
// ---------------------------------------------------------------------------
__global__ __launch_bounds__(256) void embed_kernel(
    const float* __restrict__ robot, const float* __restrict__ human,
    const float* __restrict__ wrW1, const float* __restrict__ wrb1,
    const float* __restrict__ wrW2, const float* __restrict__ wrb2,
    const float* __restrict__ whW1, const float* __restrict__ whb1,
    const float* __restrict__ whW2, const float* __restrict__ whb2,
    float* __restrict__ X)
{
  __shared__ float hs[16 * HID];   // 4 KB
  int b, rg; swz512(blockIdx.x, b, rg);
  const int t = threadIdx.x;

  for (int v = t; v < 16 * HID; v += 256) {
    const int nl = v >> 6, k = v & 63;
    const int n  = rg * 16 + nl;
    float acc;
    if (n == 0) {
      acc = wrb1[k];
      for (int j = 0; j < 9; ++j) acc = fmaf(robot[b * 9 + j], wrW1[j * HID + k], acc);
    } else {
      const float* in = human + (b * 63 + n - 1) * 5;
      acc = whb1[k];
      for (int j = 0; j < 5; ++j) acc = fmaf(in[j], whW1[j * HID + k], acc);
    }
    hs[v] = fmaxf(acc, 0.f);
  }
  __syncthreads();

  const int d = t & 127, which = t >> 7;
  float acc[8];
#pragma unroll
  for (int c = 0; c < 8; ++c) acc[c] = whb2[d];

  for (int k4 = 0; k4 < 16; ++k4) {
    float w4[4];
#pragma unroll
    for (int kk = 0; kk < 4; ++kk) w4[kk] = whW2[(4 * k4 + kk) * XD + d];
#pragma unroll
    for (int c = 0; c < 8; ++c) {
      const float4 h4 = *reinterpret_cast<const float4*>(&hs[(2 * c + which) * HID + 4 * k4]);
      acc[c] = fmaf(h4.x, w4[0], acc[c]);
      acc[c] = fmaf(h4.y, w4[1], acc[c]);
      acc[c] = fmaf(h4.z, w4[2], acc[c]);
      acc[c] = fmaf(h4.w, w4[3], acc[c]);
    }
  }
  if (rg == 0 && which == 0) {        // redo node 0 with robot weights
    float a = wrb2[d];
#pragma unroll 8
    for (int k = 0; k < HID; ++k) a = fmaf(hs[k], wrW2[k * XD + d], a);
    acc[0] = a;
  }
#pragma unroll
  for (int c = 0; c < 8; ++c) {
    const int n = rg * 16 + 2 * c + which;
    X[(size_t)(b * NN + n) * XD + d] = fmaxf(acc[c], 0.f);
  }
}

// ---------------------------------------------------------------------------
// Kernel 2/4: full UV transform (R5-validated body, swizzled block mapping).
//   UV[row][0:256]   = U' = Xin @ W1[0:128,:] + b1
//   UV[row][256:512] = V  = Xin @ W1[128:256,:]
// 512 blocks x 16 rows, 256 thr; each W1 element read once per block.
// ---------------------------------------------------------------------------
__global__ __launch_bounds__(256) void uvtrans_kernel(
    const float* __restrict__ Xin, const float* __restrict__ W1,
    const float* __restrict__ b1, float* __restrict__ UV)
{
  __shared__ float Xs[16 * XD];  // 8 KB
  int b, q; swz512(blockIdx.x, b, q);
  const int base = b * NN + q * 16;
  const int t = threadIdx.x;

  for (int idx = t; idx < 16 * XD / 4; idx += 256)
    *reinterpret_cast<float4*>(Xs + idx * 4) =
        *reinterpret_cast<const float4*>(Xin + (size_t)base * XD + idx * 4);
  __syncthreads();

  float acc0[16], acc1[16];
  const float bias = b1[t];
#pragma unroll
  for (int n = 0; n < 16; ++n) { acc0[n] = bias; acc1[n] = 0.f; }

  for (int k = 0; k < XD; k += 4) {
    float w0[4], w1[4];
#pragma unroll
    for (int kk = 0; kk < 4; ++kk) {
      w0[kk] = W1[(k + kk) * 256 + t];
      w1[kk] = W1[(128 + k + kk) * 256 + t];
    }
#pragma unroll
    for (int n = 0; n < 16; ++n) {
      const float4 x4 = *reinterpret_cast<const float4*>(&Xs[n * XD + k]);
      acc0[n] = fmaf(x4.x, w0[0], acc0[n]);
      acc0[n] = fmaf(x4.y, w0[1], acc0[n]);
      acc0[n] = fmaf(x4.z, w0[2], acc0[n]);
      acc0[n] = fmaf(x4.w, w0[3], acc0[n]);
      acc1[n] = fmaf(x4.x, w1[0], acc1[n]);
      acc1[n] = fmaf(x4.y, w1[1], acc1[n]);
      acc1[n] = fmaf(x4.z, w1[2], acc1[n]);
      acc1[n] = fmaf(x4.w, w1[3], acc1[n]);
    }
  }
#pragma unroll
  for (int n = 0; n < 16; ++n) {
    UV[(size_t)(base + n) * 512 + t]       = acc0[n];
    UV[(size_t)(base + n) * 512 + 256 + t] = acc1[n];
  }
}

// ---------------------------------------------------------------------------
// Kernel 3/5: attention (R13 body minus in-kernel T-U; U' read from UV).
// Block = (b, rg): 16 rows, 512 thr = 8 waves, LDS 70656 B -> 2 blocks/CU.
//   Vs [64][256] swizzled (chunk c -> c^(j&7), conflict-free b128)  65536 B
//   As [16][64]                                                      4096 B
//   W2s[256]                                                         1024 B
// S: lane = j; wave w rows 2w,2w+1; U' broadcast via v_readlane.
// ---------------------------------------------------------------------------
__global__ __launch_bounds__(512, 4) void attn_kernel(
    const float* __restrict__ UV, const float* __restrict__ Xpv,
    const float* __restrict__ Xskip,
    const float* __restrict__ W2g, const float* __restrict__ b2g,
    float* __restrict__ out, int add_skip)
{
  __shared__ float smem[17664];        // 70656 B
  float* Vs  = smem;                   // [64][256] swizzled
  float* As  = smem + 16384;           // [16][64]
  float* W2s = smem + 17408;           // [256]

  int b, rg; swz512(blockIdx.x, b, rg);
  const int t = threadIdx.x;
  const int w = t >> 6, l = t & 63;
  const float* UVb = UV + (size_t)b * NN * 512;

  // ---- stage V (swizzled) + W2; U' rows -> registers ----
  for (int cc = t; cc < NN * 64; cc += 512) {
    const int j = cc >> 6, c = cc & 63;
    const float4 v = *reinterpret_cast<const float4*>(UVb + j * 512 + 256 + (c << 2));
    *reinterpret_cast<float4*>(Vs + j * 256 + ((c ^ (j & 7)) << 2)) = v;
  }
  if (t < 64)
    reinterpret_cast<float4*>(W2s)[t] = reinterpret_cast<const float4*>(W2g)[t];

  const int r0 = rg * 16 + 2 * w;
  const float4 ua0 = *reinterpret_cast<const float4*>(UVb + (size_t)r0 * 512 + (l << 2));
  const float4 ua1 = *reinterpret_cast<const float4*>(UVb + (size_t)(r0 + 1) * 512 + (l << 2));
  __syncthreads();   // Vs + W2s visible

  // ---- S: e[q][j], lane = j; u broadcast via readlane ----
  float att0, att1;
  {
    const int jx = l & 7;
    float e0 = 0.f, e1 = 0.f;
    for (int c4 = 0; c4 < 64; ++c4) {
      const float4 v4 = *reinterpret_cast<const float4*>(&Vs[l * 256 + ((c4 ^ jx) << 2)]);
      const float4 w4 = *reinterpret_cast<const float4*>(&W2s[c4 << 2]);   // broadcast
      const float4 u0 = make_float4(rl_f(ua0.x, c4), rl_f(ua0.y, c4),
                                    rl_f(ua0.z, c4), rl_f(ua0.w, c4));
      const float4 u1 = make_float4(rl_f(ua1.x, c4), rl_f(ua1.y, c4),
                                    rl_f(ua1.z, c4), rl_f(ua1.w, c4));
      e0 = fmaf(fmaxf(u0.x + v4.x, 0.f), w4.x, e0);
      e0 = fmaf(fmaxf(u0.y + v4.y, 0.f), w4.y, e0);
      e0 = fmaf(fmaxf(u0.z + v4.z, 0.f), w4.z, e0);
      e0 = fmaf(fmaxf(u0.w + v4.w, 0.f), w4.w, e0);
      e1 = fmaf(fmaxf(u1.x + v4.x, 0.f), w4.x, e1);
      e1 = fmaf(fmaxf(u1.y + v4.y, 0.f), w4.y, e1);
      e1 = fmaf(fmaxf(u1.z + v4.z, 0.f), w4.z, e1);
      e1 = fmaf(fmaxf(u1.w + v4.w, 0.f), w4.w, e1);
    }
    const float bias2 = b2g[0];
    // q = 0  (row r0; robot row only when r0 == 0)
    {
      float s = e0 + bias2;
      s = s > 0.f ? s : NEG_SLOPE * s;
      if (r0 > 0 && l == 0) s = MASK_VAL;
      float m = s;
#pragma unroll
      for (int off = 32; off > 0; off >>= 1) m = fmaxf(m, __shfl_xor(m, off));
      const float p = __expf(s - m);
      float sum = p;
#pragma unroll
      for (int off = 32; off > 0; off >>= 1) sum += __shfl_xor(sum, off);
      att0 = p / sum;
    }
    // q = 1  (row r0+1 >= 1 always -> always masked at j==0)
    {
      float s = e1 + bias2;
      s = s > 0.f ? s : NEG_SLOPE * s;
      if (l == 0) s = MASK_VAL;
      float m = s;
#pragma unroll
      for (int off = 32; off > 0; off >>= 1) m = fmaxf(m, __shfl_xor(m, off));
      const float p = __expf(s - m);
      float sum = p;
#pragma unroll
      for (int off = 32; off > 0; off >>= 1) sum += __shfl_xor(sum, off);
      att1 = p / sum;
    }
  }
  As[(2 * w) * 64 + l]     = att0;
  As[(2 * w + 1) * 64 + l] = att1;
  __syncthreads();

  // ---- PV: H[row] = att[row] @ Xpv ----
  const int grp = t >> 5, d4 = (t & 31) << 2;
  const int row = rg * 16 + grp;
  float4 a = {0.f, 0.f, 0.f, 0.f};
  const float* Xb = Xpv + (size_t)b * NN * XD;
#pragma unroll 4
  for (int j = 0; j < NN; ++j) {
    const float4 x4 = *reinterpret_cast<const float4*>(&Xb[j * XD + d4]);
    const float wA = As[grp * 64 + j];
    FMA4(a, wA, x4);
  }
  if (add_skip) {   // out = H2 + H1 + X ; Xpv IS H1 here
    const float4 h1 = *reinterpret_cast<const float4*>(&Xb[row * XD + d4]);
    const float4 x0 = *reinterpret_cast<const float4*>(&Xskip[((size_t)(b * NN + row)) * XD + d4]);
    a.x += h1.x + x0.x; a.y += h1.y + x0.y; a.z += h1.z + x0.z; a.w += h1.w + x0.w;
  }
  *reinterpret_cast<float4*>(&out[((size_t)(b * NN + row)) * XD + d4]) = a;
}

// ---------------------------------------------------------------------------
extern "C" void kernel_launch(void* const* d_in, const int* in_sizes, int n_in,
                              void* d_out, int out_size, void* d_ws, size_t ws_size,
                              hipStream_t stream) {
  const float* robot = (const float*)d_in[0];
  const float* human = (const float*)d_in[1];
  const float* wrW1  = (const float*)d_in[2];
  const float* wrb1  = (const float*)d_in[3];
  const float* wrW2  = (const float*)d_in[4];
  const float* wrb2  = (const float*)d_in[5];
  const float* whW1  = (const float*)d_in[6];
  const float* whb1  = (const float*)d_in[7];
  const float* whW2  = (const float*)d_in[8];
  const float* whb2  = (const float*)d_in[9];
  const float* g0W1  = (const float*)d_in[10];
  const float* g0b1  = (const float*)d_in[11];
  const float* g0W2  = (const float*)d_in[12];
  const float* g0b2  = (const float*)d_in[13];
  const float* g1W1  = (const float*)d_in[14];
  const float* g1b1  = (const float*)d_in[15];
  const float* g1W2  = (const float*)d_in[16];
  const float* g1b2  = (const float*)d_in[17];
  float* out = (float*)d_out;

  float* Xg  = (float*)d_ws;                       //  4 MB [B,64,128]
  float* H1g = Xg  + (size_t)Bz * NN * XD;         //  4 MB [B,64,128]
  float* UVg = H1g + (size_t)Bz * NN * XD;         // 16 MB [B*64,512]

  embed_kernel<<<Bz * 4, 256, 0, stream>>>(robot, human, wrW1, wrb1, wrW2, wrb2,
                                           whW1, whb1, whW2, whb2, Xg);
  uvtrans_kernel<<<Bz * 4, 256, 0, stream>>>(Xg, g0W1, g0b1, UVg);
  attn_kernel<<<Bz * 4, 512, 0, stream>>>(UVg, Xg, nullptr, g0W2, g0b2, H1g, 0);
  uvtrans_kernel<<<Bz * 4, 256, 0, stream>>>(H1g, g1W1, g1b1, UVg);
  attn_kernel<<<Bz * 4, 512, 0, stream>>>(UVg, H1g, Xg, g1W2, g1b2, out, 1);
}